// Round 14
// baseline (154.012 us; speedup 1.0000x reference)
//
#include <hip/hip_runtime.h>

#define N_NODES 150000
#define N_EDGES 2400000
#define F_IN    22
#define HID     32
#define N_CLS   6
#define BN_EPS  1e-5f

#define BSHIFT  8
#define BMASK   255
#define NB      ((N_NODES + BMASK) >> BSHIFT)       // 586 buckets of 256 nodes
#define NBLK_BIN 256                                // one bin block per CU
#define CHUNK   ((N_EDGES + NBLK_BIN - 1) / NBLK_BIN)   // 9375 edges per block
#define CHUNK_H 8192
#define NBLK_H  ((N_EDGES + CHUNK_H - 1) / CHUNK_H) // 293 hist blocks
#define EMB_NPB 64                                  // nodes per embed block
#define NBLK_EMB ((N_NODES + EMB_NPB - 1) / EMB_NPB)    // 2344 embed blocks
#define NREP    8                                   // stats replicas

// bf16 round-to-nearest-even, packed storage helpers
__device__ __forceinline__ unsigned bf16rne(float f) {
    unsigned u = __float_as_uint(f);
    return (u + 0x7FFFu + ((u >> 16) & 1u)) >> 16;
}
__device__ __forceinline__ float bflo(unsigned p) { return __uint_as_float(p << 16); }
__device__ __forceinline__ float bfhi(unsigned p) { return __uint_as_float(p & 0xFFFF0000u); }

// ---------------------------------------------------------------------------
// K0a: bucket histogram of dst (standalone for attribution), 2-deep pipeline
// ---------------------------------------------------------------------------
__global__ void hist_kernel(const int* __restrict__ dst,
                            int* __restrict__ bcnt) {
    __shared__ int hloc[NB];
    for (int t = threadIdx.x; t < NB; t += 256) hloc[t] = 0;
    __syncthreads();
    int base = blockIdx.x * CHUNK_H;
    int end = base + CHUNK_H; if (end > N_EDGES) end = N_EDGES;
    int i = base + threadIdx.x;
    int d = 0;
    if (i < end) d = dst[i];
    while (i < end) {
        int inext = i + 256;
        int dn = 0;
        if (inext < end) dn = dst[inext];
        atomicAdd(&hloc[d >> BSHIFT], 1);
        d = dn; i = inext;
    }
    __syncthreads();
    for (int t = threadIdx.x; t < NB; t += 256)
        if (hloc[t]) atomicAdd(&bcnt[t], hloc[t]);
}

// ---------------------------------------------------------------------------
// K0b: embed (standalone for attribution): 64 nodes/block, 4 threads/node.
// ---------------------------------------------------------------------------
__global__ void embed_kernel(const float* __restrict__ x,
                             const float* __restrict__ W_emb,
                             const float* __restrict__ b_emb,
                             const float* __restrict__ W_gcn,
                             unsigned* __restrict__ hb) {
    __shared__ float sWe[F_IN * HID];
    __shared__ float sbe[HID];
    __shared__ float sWg[HID * HID];
    __shared__ float sx[EMB_NPB * 23];
    __shared__ float sh1[EMB_NPB * 33];
    __shared__ unsigned sp[EMB_NPB * 17];
    for (int t = threadIdx.x; t < F_IN * HID; t += 256) sWe[t] = W_emb[t];
    if (threadIdx.x < HID) sbe[threadIdx.x] = b_emb[threadIdx.x];
    for (int t = threadIdx.x; t < HID * HID; t += 256) sWg[t] = W_gcn[t];

    int nbase = blockIdx.x * EMB_NPB;
    int nvalid = N_NODES - nbase; if (nvalid > EMB_NPB) nvalid = EMB_NPB;

    {
        const float* xg = x + (size_t)nbase * F_IN;
        int totalx = nvalid * F_IN;
        for (int L = threadIdx.x; L < totalx; L += 256)
            sx[(L / F_IN) * 23 + (L % F_IN)] = xg[L];
    }
    __syncthreads();

    int n = threadIdx.x >> 2;
    int q = threadIdx.x & 3;
    bool act = n < nvalid;

    if (act) {
#pragma unroll
        for (int j = 0; j < 8; ++j) {
            float acc = sbe[q * 8 + j];
#pragma unroll
            for (int f = 0; f < F_IN; ++f)
                acc = fmaf(sx[n * 23 + f], sWe[f * HID + q * 8 + j], acc);
            sh1[n * 33 + q * 8 + j] = fmaxf(acc, 0.0f);
        }
    }
    __syncthreads();

    if (act) {
        float o[8];
#pragma unroll
        for (int j = 0; j < 8; ++j) o[j] = 0.0f;
#pragma unroll
        for (int f = 0; f < HID; ++f) {
            float hv = sh1[n * 33 + f];
#pragma unroll
            for (int j = 0; j < 8; ++j)
                o[j] = fmaf(hv, sWg[f * HID + q * 8 + j], o[j]);
        }
#pragma unroll
        for (int jj = 0; jj < 4; ++jj)
            sp[n * 17 + q * 4 + jj] = bf16rne(o[2 * jj]) | (bf16rne(o[2 * jj + 1]) << 16);
    }
    __syncthreads();

    int total = nvalid * 16;
    size_t gbase = (size_t)nbase * 16;
    for (int L = threadIdx.x; L < total; L += 256)
        hb[gbase + L] = sp[(L >> 4) * 17 + (L & 15)];
}

// ---------------------------------------------------------------------------
// K1: single-block exclusive scan of NB bucket counts -> boff, bcur;
//     also zeros the stats replicas
// ---------------------------------------------------------------------------
__global__ void bucket_scan_kernel(const int* __restrict__ bcnt,
                                   int* __restrict__ boff,
                                   int* __restrict__ bcur,
                                   float* __restrict__ stats) {
    int t = threadIdx.x;
    if (t < 64 * NREP) stats[t] = 0.0f;
    __shared__ int s[1024];
    int v0 = (t < NB) ? bcnt[t] : 0;
    s[t] = v0;
    __syncthreads();
#pragma unroll
    for (int o = 1; o < 1024; o <<= 1) {
        int v = (t >= o) ? s[t - o] : 0;
        __syncthreads();
        s[t] += v;
        __syncthreads();
    }
    if (t < NB) {
        int e = s[t] - v0;
        boff[t] = e;
        bcur[t] = e;
    }
    if (t == NB - 1) boff[NB] = s[t];
}

// ---------------------------------------------------------------------------
// K2: binned append, runs ALONE (write-combining needs L2 to itself).
//     2-deep pipelined passes: next edge's dst/src load issues before the
//     current edge's LDS-atomic + scattered store.
//     packed = (dst & 255) << 24 | src
// ---------------------------------------------------------------------------
__global__ void bin_edges_kernel(const int* __restrict__ src,
                                 const int* __restrict__ dst,
                                 int* __restrict__ bcur,
                                 unsigned int* __restrict__ binned) {
    __shared__ int hloc[NB];
    __shared__ int base[NB];
    __shared__ int lcur[NB];
    for (int t = threadIdx.x; t < NB; t += 512) hloc[t] = 0;
    __syncthreads();

    int cbase = blockIdx.x * CHUNK;
    int cend = cbase + CHUNK; if (cend > N_EDGES) cend = N_EDGES;

    {   // pass 1: histogram, pipelined
        int i = cbase + threadIdx.x;
        int d = 0;
        if (i < cend) d = dst[i];
        while (i < cend) {
            int inext = i + 512;
            int dn = 0;
            if (inext < cend) dn = dst[inext];
            atomicAdd(&hloc[d >> BSHIFT], 1);
            d = dn; i = inext;
        }
    }
    __syncthreads();
    for (int t = threadIdx.x; t < NB; t += 512) {
        int c = hloc[t];
        base[t] = c ? atomicAdd(&bcur[t], c) : 0;
        lcur[t] = 0;
    }
    __syncthreads();
    {   // pass 3: scatter, pipelined
        int i = cbase + threadIdx.x;
        int d = 0, s = 0;
        if (i < cend) { d = dst[i]; s = src[i]; }
        while (i < cend) {
            int inext = i + 512;
            int dn = 0, sn = 0;
            if (inext < cend) { dn = dst[inext]; sn = src[inext]; }
            int b = d >> BSHIFT;
            int r = atomicAdd(&lcur[b], 1);
            binned[base[b] + r] = ((unsigned)(d & BMASK) << 24) | (unsigned)s;
            d = dn; s = sn; i = inext;
        }
    }
}

// ---------------------------------------------------------------------------
// K3: per-bucket counting sort -> dst-sorted sorted_src + off[] + dis, AND
//     in-place bf16 pre-scale of the bucket's hb rows: hs = h * dis
// ---------------------------------------------------------------------------
__global__ void bucket_csr_kernel(const int* __restrict__ boff,
                                  const unsigned int* __restrict__ binned,
                                  int* __restrict__ sorted_src,
                                  int* __restrict__ off,
                                  float* __restrict__ dis,
                                  unsigned* __restrict__ hb) {
    __shared__ int s_cnt[256];
    __shared__ int s_scan[256];
    __shared__ int s_cur[256];
    __shared__ float dl[256];
    int b = blockIdx.x;
    int t = threadIdx.x;
    int s0 = boff[b], s1 = boff[b + 1];
    int nbase = b << BSHIFT;
    int nnode = N_NODES - nbase; if (nnode > 256) nnode = 256;

    s_cnt[t] = 0;
    __syncthreads();
    for (int k = s0 + t; k < s1; k += 256)
        atomicAdd(&s_cnt[binned[k] >> 24], 1);
    __syncthreads();

    int v = s_cnt[t];
    s_scan[t] = v;
    __syncthreads();
#pragma unroll
    for (int o = 1; o < 256; o <<= 1) {
        int u = (t >= o) ? s_scan[t - o] : 0;
        __syncthreads();
        s_scan[t] += u;
        __syncthreads();
    }
    int excl = s_scan[t] - v;
    s_cur[t] = excl;
    float d = rsqrtf(1.0f + (float)v);
    dl[t] = d;
    if (t < nnode) {
        off[nbase + t] = s0 + excl;
        dis[nbase + t] = d;
    }
    if (b == NB - 1 && t == 0) off[N_NODES] = N_EDGES;
    __syncthreads();

    for (int k = s0 + t; k < s1; k += 256) {
        unsigned p = binned[k];
        int n = (int)(p >> 24);
        int r = atomicAdd(&s_cur[n], 1);
        sorted_src[s0 + r] = (int)(p & 0xFFFFFFu);
    }

    // in-place bf16 pre-scale of this bucket's hb rows (coalesced 16 KB)
    uint2* hv = reinterpret_cast<uint2*>(hb) + (size_t)nbase * 8;
    for (int tt = t; tt < nnode * 8; tt += 256) {
        uint2 w = hv[tt];
        float dd = dl[tt >> 3];
        w.x = bf16rne(bflo(w.x) * dd) | (bf16rne(bfhi(w.x) * dd) << 16);
        w.y = bf16rne(bflo(w.y) * dd) | (bf16rne(bfhi(w.y) * dd) << 16);
        hv[tt] = w;
    }
}

// ---------------------------------------------------------------------------
// K4: per-node aggregation + fused BN-stats.  8 threads/node, pre-scaled bf16
//     rows, 8-wide ILP with idx double-buffer.
//     agg[n] = (hs[n] + sum_{in(n)} hs[s]) * dis[n]
// ---------------------------------------------------------------------------
__global__ void aggregate_kernel(const int* __restrict__ off,
                                 const int* __restrict__ sorted_src,
                                 const unsigned* __restrict__ hb,
                                 const float* __restrict__ dis,
                                 float* __restrict__ agg,
                                 float* __restrict__ stats) {
    int t = blockIdx.x * blockDim.x + threadIdx.x;
    int node = t >> 3;
    int c = t & 7;
    bool active = node < N_NODES;

    float4 ps = {0.f, 0.f, 0.f, 0.f};
    float4 pq = {0.f, 0.f, 0.f, 0.f};

    if (active) {
        const uint2* hrow = reinterpret_cast<const uint2*>(hb);
        float dn = dis[node];
        uint2 hp = hrow[(size_t)node * 8 + c];
        float4 a0, a1, a2, a3;
        a0.x = bflo(hp.x); a0.y = bfhi(hp.x);
        a0.z = bflo(hp.y); a0.w = bfhi(hp.y);
        a1 = a2 = a3 = make_float4(0.f, 0.f, 0.f, 0.f);

        int b0 = off[node], e0 = off[node + 1];
        int cnt8 = (e0 - b0) >> 3;
        int k = b0;
        int p0 = 0, p1 = 0, p2 = 0, p3 = 0, p4 = 0, p5 = 0, p6 = 0, p7 = 0;
        if (cnt8 > 0) {
            p0 = sorted_src[k];     p1 = sorted_src[k + 1];
            p2 = sorted_src[k + 2]; p3 = sorted_src[k + 3];
            p4 = sorted_src[k + 4]; p5 = sorted_src[k + 5];
            p6 = sorted_src[k + 6]; p7 = sorted_src[k + 7];
        }
        for (int it = 0; it < cnt8; ++it) {
            int kn = k + 8;
            int n0 = p0, n1 = p1, n2 = p2, n3 = p3;
            int n4 = p4, n5 = p5, n6 = p6, n7 = p7;
            if (it + 1 < cnt8) {
                n0 = sorted_src[kn];     n1 = sorted_src[kn + 1];
                n2 = sorted_src[kn + 2]; n3 = sorted_src[kn + 3];
                n4 = sorted_src[kn + 4]; n5 = sorted_src[kn + 5];
                n6 = sorted_src[kn + 6]; n7 = sorted_src[kn + 7];
            }
            uint2 v0 = hrow[(size_t)p0 * 8 + c];
            uint2 v1 = hrow[(size_t)p1 * 8 + c];
            uint2 v2 = hrow[(size_t)p2 * 8 + c];
            uint2 v3 = hrow[(size_t)p3 * 8 + c];
            uint2 v4 = hrow[(size_t)p4 * 8 + c];
            uint2 v5 = hrow[(size_t)p5 * 8 + c];
            uint2 v6 = hrow[(size_t)p6 * 8 + c];
            uint2 v7 = hrow[(size_t)p7 * 8 + c];
            a0.x += bflo(v0.x); a0.y += bfhi(v0.x); a0.z += bflo(v0.y); a0.w += bfhi(v0.y);
            a1.x += bflo(v1.x); a1.y += bfhi(v1.x); a1.z += bflo(v1.y); a1.w += bfhi(v1.y);
            a2.x += bflo(v2.x); a2.y += bfhi(v2.x); a2.z += bflo(v2.y); a2.w += bfhi(v2.y);
            a3.x += bflo(v3.x); a3.y += bfhi(v3.x); a3.z += bflo(v3.y); a3.w += bfhi(v3.y);
            a0.x += bflo(v4.x); a0.y += bfhi(v4.x); a0.z += bflo(v4.y); a0.w += bfhi(v4.y);
            a1.x += bflo(v5.x); a1.y += bfhi(v5.x); a1.z += bflo(v5.y); a1.w += bfhi(v5.y);
            a2.x += bflo(v6.x); a2.y += bfhi(v6.x); a2.z += bflo(v6.y); a2.w += bfhi(v6.y);
            a3.x += bflo(v7.x); a3.y += bfhi(v7.x); a3.z += bflo(v7.y); a3.w += bfhi(v7.y);
            p0 = n0; p1 = n1; p2 = n2; p3 = n3;
            p4 = n4; p5 = n5; p6 = n6; p7 = n7;
            k = kn;
        }
        for (; k < e0; ++k) {
            int s = sorted_src[k];
            uint2 v = hrow[(size_t)s * 8 + c];
            a0.x += bflo(v.x); a0.y += bfhi(v.x);
            a0.z += bflo(v.y); a0.w += bfhi(v.y);
        }
        float4 o;
        o.x = (a0.x + a1.x + a2.x + a3.x) * dn;
        o.y = (a0.y + a1.y + a2.y + a3.y) * dn;
        o.z = (a0.z + a1.z + a2.z + a3.z) * dn;
        o.w = (a0.w + a1.w + a2.w + a3.w) * dn;
        reinterpret_cast<float4*>(agg)[(size_t)node * 8 + c] = o;
        ps = o;
        pq.x = o.x * o.x; pq.y = o.y * o.y; pq.z = o.z * o.z; pq.w = o.w * o.w;
    }

    __shared__ float S[256 * 4];
    __shared__ float Q[256 * 4];
    S[threadIdx.x * 4 + 0] = ps.x; S[threadIdx.x * 4 + 1] = ps.y;
    S[threadIdx.x * 4 + 2] = ps.z; S[threadIdx.x * 4 + 3] = ps.w;
    Q[threadIdx.x * 4 + 0] = pq.x; Q[threadIdx.x * 4 + 1] = pq.y;
    Q[threadIdx.x * 4 + 2] = pq.z; Q[threadIdx.x * 4 + 3] = pq.w;
    __syncthreads();
    if (threadIdx.x < 32) {
        int cc = threadIdx.x >> 2, j = threadIdx.x & 3;
        float s = 0.0f, q = 0.0f;
#pragma unroll
        for (int w = 0; w < 32; ++w) {
            int tid = (w << 3) | cc;
            s += S[tid * 4 + j];
            q += Q[tid * 4 + j];
        }
        float* rep = stats + 64 * (blockIdx.x & (NREP - 1));
        atomicAdd(&rep[threadIdx.x], s);
        atomicAdd(&rep[32 + threadIdx.x], q);
    }
}

// ---------------------------------------------------------------------------
// K5: out = relu(agg*A + B) @ W_cls + b_cls   (BN fold from NREP stat replicas)
// ---------------------------------------------------------------------------
__global__ void cls_kernel(const float* __restrict__ agg,
                           const float* __restrict__ stats,
                           const float* __restrict__ gamma,
                           const float* __restrict__ beta,
                           const float* __restrict__ W_cls,
                           const float* __restrict__ b_cls,
                           float* __restrict__ out) {
    __shared__ float sA[HID];
    __shared__ float sB[HID];
    __shared__ float sW[HID * N_CLS];
    __shared__ float sb[N_CLS];
    if (threadIdx.x < HID) {
        float sum = 0.0f, sq = 0.0f;
#pragma unroll
        for (int r = 0; r < NREP; ++r) {
            sum += stats[r * 64 + threadIdx.x];
            sq  += stats[r * 64 + 32 + threadIdx.x];
        }
        const float invN = 1.0f / (float)N_NODES;
        float mean = sum * invN;
        float var = sq * invN - mean * mean;
        float inv = rsqrtf(var + BN_EPS);
        float A = gamma[threadIdx.x] * inv;
        sA[threadIdx.x] = A;
        sB[threadIdx.x] = beta[threadIdx.x] - mean * A;
    }
    for (int t = threadIdx.x; t < HID * N_CLS; t += blockDim.x) sW[t] = W_cls[t];
    if (threadIdx.x < N_CLS) sb[threadIdx.x] = b_cls[threadIdx.x];
    __syncthreads();

    int i = blockIdx.x * blockDim.x + threadIdx.x;
    if (i >= N_NODES) return;

    float acc[N_CLS];
#pragma unroll
    for (int c = 0; c < N_CLS; ++c) acc[c] = sb[c];
#pragma unroll
    for (int f = 0; f < HID; ++f) {
        float t = fmaxf(fmaf(agg[(size_t)i * HID + f], sA[f], sB[f]), 0.0f);
#pragma unroll
        for (int c = 0; c < N_CLS; ++c) acc[c] = fmaf(t, sW[f * N_CLS + c], acc[c]);
    }
#pragma unroll
    for (int c = 0; c < N_CLS; ++c) out[(size_t)i * N_CLS + c] = acc[c];
}

// ---------------------------------------------------------------------------
extern "C" void kernel_launch(void* const* d_in, const int* in_sizes, int n_in,
                              void* d_out, int out_size, void* d_ws, size_t ws_size,
                              hipStream_t stream) {
    const float* x     = (const float*)d_in[0];
    const int*   edge  = (const int*)d_in[1];   // [2, E] int32
    const float* W_emb = (const float*)d_in[2];
    const float* b_emb = (const float*)d_in[3];
    const float* W_gcn = (const float*)d_in[4];
    // d_in[5] = b_gcn: cancels exactly in BatchNorm -> skip
    const float* gamma = (const float*)d_in[6];
    const float* beta  = (const float*)d_in[7];
    const float* W_cls = (const float*)d_in[8];
    const float* b_cls = (const float*)d_in[9];
    float* out = (float*)d_out;

    // workspace layout (~49 MB)
    unsigned*     hb         = (unsigned*)d_ws;                 // N*HID/2 uints (bf16 x2)
    float*        agg        = (float*)(hb + (size_t)N_NODES * HID / 2);  // N*HID
    float*        dis        = agg + (size_t)N_NODES * HID;     // N
    int*          off        = (int*)(dis + N_NODES);           // N+1
    int*          bcnt       = off + N_NODES + 1;               // NB
    int*          boff       = bcnt + NB;                       // NB+1
    int*          bcur       = boff + NB + 1;                   // NB
    unsigned int* binned     = (unsigned int*)(bcur + NB);      // E
    int*          sorted_src = (int*)(binned + N_EDGES);        // E
    float*        stats      = (float*)(sorted_src + N_EDGES);  // 64*NREP

    hipMemsetAsync(bcnt, 0, NB * sizeof(int), stream);

    const int* src = edge;
    const int* dst = edge + N_EDGES;

    hist_kernel<<<NBLK_H, 256, 0, stream>>>(dst, bcnt);
    embed_kernel<<<NBLK_EMB, 256, 0, stream>>>(x, W_emb, b_emb, W_gcn, hb);
    bucket_scan_kernel<<<1, 1024, 0, stream>>>(bcnt, boff, bcur, stats);
    bin_edges_kernel<<<NBLK_BIN, 512, 0, stream>>>(src, dst, bcur, binned);
    bucket_csr_kernel<<<NB, 256, 0, stream>>>(boff, binned, sorted_src, off, dis, hb);
    aggregate_kernel<<<(N_NODES * 8 + 255) / 256, 256, 0, stream>>>(off, sorted_src,
                                                                    hb, dis, agg, stats);
    cls_kernel<<<(N_NODES + 255) / 256, 256, 0, stream>>>(agg, stats, gamma, beta,
                                                          W_cls, b_cls, out);
}